// Round 14
// baseline (458.292 us; speedup 1.0000x reference)
//
#include <hip/hip_runtime.h>
#include <stdint.h>

#define DEV __device__ __forceinline__

typedef __attribute__((__ext_vector_type__(8))) short short8;
typedef __attribute__((__ext_vector_type__(4))) float f32x4;
typedef __attribute__((__ext_vector_type__(16))) float f32x16;
typedef __attribute__((__ext_vector_type__(4))) unsigned short ushort4_t;
typedef __attribute__((__ext_vector_type__(4))) _Float16 half4;
typedef __attribute__((__ext_vector_type__(8))) _Float16 half8;

// ---------- helpers ----------
DEV unsigned short f2bf(float f) {
  union { float f; unsigned u; } x; x.f = f;
  unsigned u = x.u;
  unsigned r = (u + 0x7FFFu + ((u >> 16) & 1u)) >> 16;  // RNE
  return (unsigned short)r;
}

DEV unsigned short f2h(float f) {
  _Float16 h = (_Float16)f;
  unsigned short u;
  __builtin_memcpy(&u, &h, 2);
  return u;
}

DEV void gload_lds16(const void* g, void* l) {
  __builtin_amdgcn_global_load_lds(
      (const __attribute__((address_space(1))) unsigned int*)g,
      (__attribute__((address_space(3))) unsigned int*)l,
      16, 0, 0);
}

DEV short8 ld_g8(const unsigned short* p) { return *(const short8*)p; }
DEV short8 ld_s8(const unsigned short* p) { return *(const short8*)p; }
DEV half4 ld_h4(const unsigned short* p) {
  half4 r; __builtin_memcpy(&r, p, 8); return r;
}

// ---------- mask dtype detection ----------
__global__ void detect_mask_fmt(const unsigned int* __restrict__ mask, int* __restrict__ flag) {
  if (threadIdx.x == 0 && blockIdx.x == 0) {
    int fmt = 1;
    for (int i = 0; i < 256; ++i) {
      unsigned u = mask[i];
      if (u == 0x3F800000u) { fmt = 2; break; }
      if ((u & 0xFFFFFF00u) != 0u) { fmt = 0; break; }
    }
    *flag = fmt;
  }
}

// ---------- mask -> packed bits pm[(bh*64 + t)*2048 + q], bit j = mask[q][32t+j] ----------
__global__ void pack_mask(const unsigned char* __restrict__ m8,
                          const unsigned int* __restrict__ m32,
                          const int* __restrict__ mfmt,
                          unsigned int* __restrict__ pm) {
  __shared__ unsigned int tile[32 * 65];
  const int bh = blockIdx.x >> 6;
  const int q0 = (blockIdx.x & 63) * 32;
  const int fmt = *mfmt;
  const int tid = threadIdx.x;
#pragma unroll
  for (int rnd = 0; rnd < 8; ++rnd) {
    int w = tid + rnd * 256;
    int q = w >> 6, t = w & 63;
    size_t sb = ((size_t)(bh * 2048 + q0 + q)) * 2048 + t * 32;
    unsigned bits = 0;
    if (fmt == 0) {
      uint4 a = *(const uint4*)(m8 + sb);
      uint4 bq = *(const uint4*)(m8 + sb + 16);
      unsigned wa[8] = {a.x, a.y, a.z, a.w, bq.x, bq.y, bq.z, bq.w};
#pragma unroll
      for (int c = 0; c < 8; ++c)
#pragma unroll
        for (int e = 0; e < 4; ++e)
          bits |= (((wa[c] >> (8 * e)) & 0xFFu) ? 1u : 0u) << (c * 4 + e);
    } else {
#pragma unroll
      for (int c = 0; c < 8; ++c) {
        uint4 v = *(const uint4*)(m32 + sb + c * 4);
        bits |= (v.x ? 1u : 0u) << (c * 4);
        bits |= (v.y ? 1u : 0u) << (c * 4 + 1);
        bits |= (v.z ? 1u : 0u) << (c * 4 + 2);
        bits |= (v.w ? 1u : 0u) << (c * 4 + 3);
      }
    }
    tile[q * 65 + t] = bits;
  }
  __syncthreads();
#pragma unroll
  for (int rnd = 0; rnd < 8; ++rnd) {
    int w = tid + rnd * 256;
    int t = w >> 5, q = w & 31;
    pm[((size_t)bh * 64 + t) * 2048 + q0 + q] = tile[q * 65 + t];
  }
}

// ---------- fused fp32 -> bf16 convert ----------
__global__ void cvt_all(const float* __restrict__ q, const float* __restrict__ k,
                        const float* __restrict__ v,
                        const float* __restrict__ wq, const float* __restrict__ wk,
                        const float* __restrict__ wv, const float* __restrict__ wo,
                        unsigned short* __restrict__ Xq, unsigned short* __restrict__ Xk,
                        unsigned short* __restrict__ Xv, unsigned short* __restrict__ Wqb,
                        unsigned short* __restrict__ Wkb, unsigned short* __restrict__ Wvb,
                        unsigned short* __restrict__ Wob) {
  int i = blockIdx.x * 256 + threadIdx.x;
  const float* src; unsigned short* dst; int off;
  if (i < 1048576)      { src = q;  dst = Xq;  off = i; }
  else if (i < 2097152) { src = k;  dst = Xk;  off = i - 1048576; }
  else if (i < 3145728) { src = v;  dst = Xv;  off = i - 2097152; }
  else if (i < 3407872) { src = wq; dst = Wqb; off = i - 3145728; }
  else if (i < 3670016) { src = wk; dst = Wkb; off = i - 3407872; }
  else if (i < 3932160) { src = wv; dst = Wvb; off = i - 3670016; }
  else                  { src = wo; dst = Wob; off = i - 3932160; }
  float4 vv = ((const float4*)src)[off];
  ushort4_t r;
  r.x = f2bf(vv.x); r.y = f2bf(vv.y); r.z = f2bf(vv.z); r.w = f2bf(vv.w);
  ((ushort4_t*)dst)[off] = r;
}

// ---------- fused QKV projection GEMM ----------
__global__ __launch_bounds__(256, 2) void proj_gemm(
    const unsigned short* __restrict__ Xq, const unsigned short* __restrict__ Xk,
    const unsigned short* __restrict__ Xv,
    const unsigned short* __restrict__ Wqb, const unsigned short* __restrict__ Wkb,
    const unsigned short* __restrict__ Wvb,
    const float* __restrict__ bq, const float* __restrict__ bk, const float* __restrict__ bv,
    unsigned short* __restrict__ QP, unsigned short* __restrict__ KP,
    unsigned short* __restrict__ VT) {
  const int tid = threadIdx.x;
  const int wid = tid >> 6, lane = tid & 63;
  const int l16 = lane & 15, hi = lane >> 4;
  const int m0 = blockIdx.x * 128;
  const int sel = blockIdx.y >> 3;
  const int n0 = (blockIdx.y & 7) * 128;

  const unsigned short* X; const unsigned short* W; const float* bias; unsigned short* out;
  if (sel == 0)      { X = Xq; W = Wqb; bias = bq; out = QP; }
  else if (sel == 1) { X = Xk; W = Wkb; bias = bk; out = KP; }
  else               { X = Xv; W = Wvb; bias = bv; out = VT; }

  __shared__ unsigned short stage[2 * 128 * 32];

  f32x4 acc[4][4] = {};
  const int wm = (wid >> 1) * 64, wn = (wid & 1) * 64;
  const int aoff = (sel == 2) ? 4096 : 0;
  const int boff = 4096 - aoff;

  for (int kt = 0; kt < 1024; kt += 32) {
#pragma unroll
    for (int t = 0; t < 4; ++t) {
      int g = wid * 4 + t;
      int c = g & 7;
      int row = c * 16 + (lane >> 2);
      int ko = (lane & 3) * 8;
      const unsigned short* src = (g < 8)
          ? (X + (size_t)(m0 + row) * 1024 + kt + ko)
          : (W + (size_t)(n0 + row) * 1024 + kt + ko);
      gload_lds16(src, (unsigned short*)((char*)stage + g * 1024));
    }
    __syncthreads();

    short8 af[4], bfr[4];
#pragma unroll
    for (int i = 0; i < 4; ++i)
      af[i] = ld_s8(&stage[aoff + (wm + i * 16 + l16) * 32 + hi * 8]);
#pragma unroll
    for (int j = 0; j < 4; ++j)
      bfr[j] = ld_s8(&stage[boff + (wn + j * 16 + l16) * 32 + hi * 8]);
#pragma unroll
    for (int i = 0; i < 4; ++i)
#pragma unroll
      for (int j = 0; j < 4; ++j)
        acc[i][j] = __builtin_amdgcn_mfma_f32_16x16x32_bf16(af[i], bfr[j], acc[i][j], 0, 0, 0);
    __syncthreads();
  }

  if (sel != 2) {
#pragma unroll
    for (int j = 0; j < 4; ++j) {
      int feat = n0 + wn + j * 16 + l16;
      float bi = bias[feat];
      int h = feat >> 6, d = feat & 63;
#pragma unroll
      for (int i = 0; i < 4; ++i) {
#pragma unroll
        for (int r = 0; r < 4; ++r) {
          int m = m0 + wm + i * 16 + hi * 4 + r;
          int b = m >> 11, n = m & 2047;
          float v = acc[i][j][r] + bi;
          out[(((size_t)(b * 16 + h)) * 2048 + n) * 64 + d] = f2bf(v);
        }
      }
    }
  } else {
#pragma unroll
    for (int j = 0; j < 4; ++j) {
      int tc0 = m0 + wn + j * 16;
      int b = tc0 >> 11, n = tc0 & 2047;
#pragma unroll
      for (int i = 0; i < 4; ++i) {
#pragma unroll
        for (int r = 0; r < 4; ++r) {
          int feat = n0 + wm + i * 16 + hi * 4 + r;
          int h = feat >> 6, d = feat & 63;
          float v = acc[i][j][r] + bias[feat];
          out[((size_t)(b * 16 + h) * 64 + d) * 2048 + n + l16] = f2h(v);
        }
      }
    }
  }
}

// ---------- flash attention: k-split 2-way, wave-private barrier-free pipeline ----------
// grid 1024: bid = qt*32 + bh (32 qtiles of 64 q). block 256 = 4 waves:
// wave (qh = w&1, ks = w>>1): q rows qt*64+qh*32..+31, k-half ks*1024..+1023.
// Each wave stages AND consumes its own W rows (no main-loop barriers); staged-data
// readiness via counted s_waitcnt vmcnt(13). Private softmax state; 2-way LDS merge.
__global__ __launch_bounds__(256, 4) void attn_kernel(
    const unsigned short* __restrict__ Q, const unsigned short* __restrict__ K,
    const unsigned short* __restrict__ VT,
    const float* __restrict__ weights,
    const unsigned int* __restrict__ pm,
    unsigned short* __restrict__ O) {
  const int bid = blockIdx.x;
  const int qt = bid >> 5, bh = bid & 31;
  const int b = bh >> 4, h = bh & 15;
  const int tid = threadIdx.x;
  const int w4 = tid >> 6, lane = tid & 63;
  const int qh = w4 & 1, ks = w4 >> 1;
  const int l31 = lane & 31, hh = lane >> 5;
  const size_t bh_nd = (size_t)bh * 2048 * 64;
  const int q0 = qt * 64;
  const int qg = q0 + qh * 32 + l31;

  short8 qf0 = ld_g8(Q + bh_nd + (size_t)qg * 64 + 0  + hh * 8);
  short8 qf1 = ld_g8(Q + bh_nd + (size_t)qg * 64 + 16 + hh * 8);
  short8 qf2 = ld_g8(Q + bh_nd + (size_t)qg * 64 + 32 + hh * 8);
  short8 qf3 = ld_g8(Q + bh_nd + (size_t)qg * 64 + 48 + hh * 8);

  __shared__ float wlds[2][2][64 * 32];   // [ks][dbuf][64 rows x 32 k] = 32 KB
  __shared__ float mlbuf[128];            // merge m/l exchange

  const float* wsrc = weights + (size_t)bh * 2048 * 2048;
  const unsigned short* vsrc = VT + bh_nd;
  const unsigned short* ksrc = K + bh_nd;
  const unsigned int* pmsrc = pm + (size_t)(bh * 64) * 2048 + qg;
  const int wswz = 4 * ((lane & 7) ^ (lane >> 3));
  const int wrow_s = q0 + qh * 32 + (lane >> 3);   // + i*8

  // stage 32 rows x 32 k fp32 (4 KB) for THIS wave into wlds[ks][NXT]
#define STAGE(NXT, KTILE)                                                     \
  {                                                                           \
    _Pragma("unroll")                                                         \
    for (int i_ = 0; i_ < 4; ++i_)                                            \
      gload_lds16(wsrc + (size_t)(wrow_s + i_ * 8) * 2048                     \
                      + (size_t)(KTILE) * 32 + wswz,                          \
                  &wlds[ks][NXT][(qh * 32 + i_ * 8) * 32]);                   \
  }

  f32x16 o0 = {}, o1 = {};
  float mrow = -1e30f, lrow = 0.f;

  STAGE(0, ks * 32)

  for (int t = 0; t < 32; ++t) {
    const int cur = t & 1;
    const int ktile = ks * 32 + t;
    const int kt0 = ktile * 32;

    // ---- K / pm / V direct loads (L2-resident K,V; compiler-managed waits)
    short8 kf0 = ld_g8(ksrc + (size_t)(kt0 + l31) * 64 + 0  + hh * 8);
    short8 kf1 = ld_g8(ksrc + (size_t)(kt0 + l31) * 64 + 16 + hh * 8);
    short8 kf2 = ld_g8(ksrc + (size_t)(kt0 + l31) * 64 + 32 + hh * 8);
    short8 kf3 = ld_g8(ksrc + (size_t)(kt0 + l31) * 64 + 48 + hh * 8);
    unsigned mw = pmsrc[(size_t)ktile * 2048];
    half4 vva[4], vvb[4];
#pragma unroll
    for (int cc = 0; cc < 4; ++cc) {
      vva[cc] = ld_h4(vsrc + (size_t)l31 * 2048 + kt0 + 4 * hh + 8 * cc);
      vvb[cc] = ld_h4(vsrc + (size_t)(32 + l31) * 2048 + kt0 + 4 * hh + 8 * cc);
    }

    // ---- issue next tile's W stage (stays in flight under compute)
    if (t < 31) STAGE(cur ^ 1, ktile + 1)

    // ---- ensure W(cur) staged (stage(t) 4 newest ops stay outstanding)
    asm volatile("s_waitcnt vmcnt(13)" ::: "memory");

    // ---- QK^T (S^T): lane q = l31(+qh,qt), k = (r&3)+8*(r>>2)+4*hh
    f32x16 s = {};
    s = __builtin_amdgcn_mfma_f32_32x32x16_bf16(kf0, qf0, s, 0, 0, 0);
    s = __builtin_amdgcn_mfma_f32_32x32x16_bf16(kf1, qf1, s, 0, 0, 0);
    s = __builtin_amdgcn_mfma_f32_32x32x16_bf16(kf2, qf2, s, 0, 0, 0);
    s = __builtin_amdgcn_mfma_f32_32x32x16_bf16(kf3, qf3, s, 0, 0, 0);

    // ---- weights from own LDS rows
    const float* wrow = &wlds[ks][cur][(qh * 32 + l31) * 32];
    f32x4 wv[4];
    wv[0] = *(const f32x4*)&wrow[4 * ((hh + 0) ^ (l31 & 7))];
    wv[1] = *(const f32x4*)&wrow[4 * ((hh + 2) ^ (l31 & 7))];
    wv[2] = *(const f32x4*)&wrow[4 * ((hh + 4) ^ (l31 & 7))];
    wv[3] = *(const f32x4*)&wrow[4 * ((hh + 6) ^ (l31 & 7))];

    unsigned mb = mw >> (4 * hh);
#pragma unroll
    for (int r = 0; r < 16; ++r) {
      bool mk = (mb >> ((r & 3) + 8 * (r >> 2))) & 1;
      s[r] = mk ? -INFINITY : s[r] * 0.125f * wv[r >> 2][r & 3];
    }

    // ---- online softmax (private per wave)
    float tm = s[0];
#pragma unroll
    for (int r = 1; r < 16; ++r) tm = fmaxf(tm, s[r]);
    float tm2 = fmaxf(tm, __shfl_xor(tm, 32));
    if (__any(tm2 > mrow)) {
      float mnew = fmaxf(mrow, tm2);
      float sc = __expf(mrow - mnew);
      lrow *= sc;
      o0 *= sc;
      o1 *= sc;
      mrow = mnew;
    }
    float ps = 0.f;
#pragma unroll
    for (int r = 0; r < 16; ++r) {
      s[r] = __expf(s[r] - mrow);
      ps += s[r];
    }
    lrow += ps;

    half8 pa0, pa1;
#pragma unroll
    for (int r = 0; r < 8; ++r) {
      pa0[r] = (_Float16)s[r];
      pa1[r] = (_Float16)s[8 + r];
    }

    // ---- PV (permuted-k fragments; V from regs)
    {
      half8 vf;
#pragma unroll
      for (int e = 0; e < 4; ++e) { vf[e] = vva[0][e]; vf[4 + e] = vva[1][e]; }
      o0 = __builtin_amdgcn_mfma_f32_32x32x16_f16(vf, pa0, o0, 0, 0, 0);
#pragma unroll
      for (int e = 0; e < 4; ++e) { vf[e] = vva[2][e]; vf[4 + e] = vva[3][e]; }
      o0 = __builtin_amdgcn_mfma_f32_32x32x16_f16(vf, pa1, o0, 0, 0, 0);
#pragma unroll
      for (int e = 0; e < 4; ++e) { vf[e] = vvb[0][e]; vf[4 + e] = vvb[1][e]; }
      o1 = __builtin_amdgcn_mfma_f32_32x32x16_f16(vf, pa0, o1, 0, 0, 0);
#pragma unroll
      for (int e = 0; e < 4; ++e) { vf[e] = vvb[2][e]; vf[4 + e] = vvb[3][e]; }
      o1 = __builtin_amdgcn_mfma_f32_32x32x16_f16(vf, pa1, o1, 0, 0, 0);
    }
  }

  // ---- 2-way merge: ks=1 publishes to LDS; ks=0 merges + stores ----
  lrow += __shfl_xor(lrow, 32);
  const int prow = qh * 32 + l31;
  __syncthreads();                        // all main-loop LDS traffic done
  float* pb = &wlds[0][0][0];             // 64 rows x 64 f32 = 16 KB
  if (ks == 1) {
#pragma unroll
    for (int j = 0; j < 4; ++j) {
      f32x4 a0 = { o0[4 * j], o0[4 * j + 1], o0[4 * j + 2], o0[4 * j + 3] };
      f32x4 a1 = { o1[4 * j], o1[4 * j + 1], o1[4 * j + 2], o1[4 * j + 3] };
      *(f32x4*)&pb[prow * 64 + 8 * j + 4 * hh] = a0;
      *(f32x4*)&pb[prow * 64 + 32 + 8 * j + 4 * hh] = a1;
    }
    if (hh == 0) { mlbuf[prow] = mrow; mlbuf[64 + prow] = lrow; }
  }
  __syncthreads();
  if (ks == 0) {
    float m1 = mlbuf[prow], l1 = mlbuf[64 + prow];
    float M = fmaxf(mrow, m1);
    float c0 = __expf(mrow - M), c1 = __expf(m1 - M);
    float inv = 1.0f / (c0 * lrow + c1 * l1);
    const size_t ob = (size_t)(b * 2048 + qg) * 1024 + h * 64;
#pragma unroll
    for (int j = 0; j < 4; ++j) {
      f32x4 p0 = *(const f32x4*)&pb[prow * 64 + 8 * j + 4 * hh];
      f32x4 p1 = *(const f32x4*)&pb[prow * 64 + 32 + 8 * j + 4 * hh];
      ushort4_t pk;
      pk.x = f2bf((c0 * o0[4 * j + 0] + c1 * p0[0]) * inv);
      pk.y = f2bf((c0 * o0[4 * j + 1] + c1 * p0[1]) * inv);
      pk.z = f2bf((c0 * o0[4 * j + 2] + c1 * p0[2]) * inv);
      pk.w = f2bf((c0 * o0[4 * j + 3] + c1 * p0[3]) * inv);
      *(ushort4_t*)&O[ob + 8 * j + 4 * hh] = pk;
      ushort4_t pk1;
      pk1.x = f2bf((c0 * o1[4 * j + 0] + c1 * p1[0]) * inv);
      pk1.y = f2bf((c0 * o1[4 * j + 1] + c1 * p1[1]) * inv);
      pk1.z = f2bf((c0 * o1[4 * j + 2] + c1 * p1[2]) * inv);
      pk1.w = f2bf((c0 * o1[4 * j + 3] + c1 * p1[3]) * inv);
      *(ushort4_t*)&O[ob + 32 + 8 * j + 4 * hh] = pk1;
    }
  }
#undef STAGE
}

// ---------- output projection GEMM (fp32 out) ----------
__global__ __launch_bounds__(256, 2) void out_gemm(
    const unsigned short* __restrict__ A, const unsigned short* __restrict__ W,
    const float* __restrict__ bias, float* __restrict__ Cout) {
  const int tid = threadIdx.x;
  const int wid = tid >> 6, lane = tid & 63;
  const int l16 = lane & 15, hi = lane >> 4;
  const int m0 = blockIdx.x * 128;
  const int n0 = blockIdx.y * 128;

  __shared__ unsigned short stage[2 * 128 * 32];
  f32x4 acc[4][4] = {};
  const int wm = (wid >> 1) * 64, wn = (wid & 1) * 64;

  for (int kt = 0; kt < 1024; kt += 32) {
#pragma unroll
    for (int t = 0; t < 4; ++t) {
      int g = wid * 4 + t;
      int c = g & 7;
      int row = c * 16 + (lane >> 2);
      int ko = (lane & 3) * 8;
      const unsigned short* src = (g < 8)
          ? (A + (size_t)(m0 + row) * 1024 + kt + ko)
          : (W + (size_t)(n0 + row) * 1024 + kt + ko);
      gload_lds16(src, (unsigned short*)((char*)stage + g * 1024));
    }
    __syncthreads();

    short8 af[4], bfr[4];
#pragma unroll
    for (int i = 0; i < 4; ++i)
      af[i] = ld_s8(&stage[(wm + i * 16 + l16) * 32 + hi * 8]);
#pragma unroll
    for (int j = 0; j < 4; ++j)
      bfr[j] = ld_s8(&stage[4096 + (wn + j * 16 + l16) * 32 + hi * 8]);
#pragma unroll
    for (int i = 0; i < 4; ++i)
#pragma unroll
      for (int j = 0; j < 4; ++j)
        acc[i][j] = __builtin_amdgcn_mfma_f32_16x16x32_bf16(af[i], bfr[j], acc[i][j], 0, 0, 0);
    __syncthreads();
  }

#pragma unroll
  for (int j = 0; j < 4; ++j) {
    int feat = n0 + wn + j * 16 + l16;
    float bi = bias[feat];
#pragma unroll
    for (int i = 0; i < 4; ++i) {
#pragma unroll
      for (int r = 0; r < 4; ++r) {
        int m = m0 + wm + i * 16 + hi * 4 + r;
        Cout[(size_t)m * 1024 + feat] = acc[i][j][r] + bi;
      }
    }
  }
}

// ---------- launch ----------
extern "C" void kernel_launch(void* const* d_in, const int* in_sizes, int n_in,
                              void* d_out, int out_size, void* d_ws, size_t ws_size,
                              hipStream_t stream) {
  const float* queries = (const float*)d_in[0];
  const float* keys    = (const float*)d_in[1];
  const float* values  = (const float*)d_in[2];
  const void*  maskp   = d_in[3];
  const float* weights = (const float*)d_in[4];
  const float* Wq = (const float*)d_in[5];
  const float* bq = (const float*)d_in[6];
  const float* Wk = (const float*)d_in[7];
  const float* bk = (const float*)d_in[8];
  const float* Wv = (const float*)d_in[9];
  const float* bv = (const float*)d_in[10];
  const float* Wo = (const float*)d_in[11];
  const float* bo = (const float*)d_in[12];

  unsigned short* ws = (unsigned short*)d_ws;
  unsigned short* Xq  = ws;                 // OB aliases Xq after proj
  unsigned short* Xk  = ws + 4194304;
  unsigned short* Xv  = ws + 8388608;
  unsigned short* Wqb = ws + 12582912;
  unsigned short* Wkb = ws + 13631488;
  unsigned short* Wvb = ws + 14680064;
  unsigned short* Wob = ws + 15728640;
  unsigned short* QP  = ws + 16777216;
  unsigned short* KP  = ws + 20971520;
  unsigned short* VPT = ws + 25165824;
  unsigned short* OB  = Xq;
  int* mflag = (int*)(ws + 29360128);
  unsigned int* pmb   = (unsigned int*)(ws + 33554432);

  detect_mask_fmt<<<1, 64, 0, stream>>>((const unsigned int*)maskp, mflag);

  cvt_all<<<16384, 256, 0, stream>>>(queries, keys, values, Wq, Wk, Wv, Wo,
                                     Xq, Xk, Xv, Wqb, Wkb, Wvb, Wob);

  proj_gemm<<<dim3(32, 24), 256, 0, stream>>>(Xq, Xk, Xv, Wqb, Wkb, Wvb,
                                              bq, bk, bv, QP, KP, VPT);

  pack_mask<<<2048, 256, 0, stream>>>((const unsigned char*)maskp,
                                      (const unsigned int*)maskp, mflag, pmb);

  attn_kernel<<<1024, 256, 0, stream>>>(QP, KP, VPT, weights, pmb, OB);

  out_gemm<<<dim3(32, 8), 256, 0, stream>>>(OB, Wob, bo, (float*)d_out);
}

// Round 15
// 359.436 us; speedup vs baseline: 1.2750x; 1.2750x over previous
//
#include <hip/hip_runtime.h>
#include <stdint.h>

#define DEV __device__ __forceinline__

typedef __attribute__((__ext_vector_type__(8))) short short8;
typedef __attribute__((__ext_vector_type__(4))) float f32x4;
typedef __attribute__((__ext_vector_type__(16))) float f32x16;
typedef __attribute__((__ext_vector_type__(4))) unsigned short ushort4_t;
typedef __attribute__((__ext_vector_type__(4))) _Float16 half4;
typedef __attribute__((__ext_vector_type__(8))) _Float16 half8;

// ---------- helpers ----------
DEV unsigned short f2bf(float f) {
  union { float f; unsigned u; } x; x.f = f;
  unsigned u = x.u;
  unsigned r = (u + 0x7FFFu + ((u >> 16) & 1u)) >> 16;  // RNE
  return (unsigned short)r;
}

DEV unsigned short f2h(float f) {
  _Float16 h = (_Float16)f;
  unsigned short u;
  __builtin_memcpy(&u, &h, 2);
  return u;
}

DEV void gload_lds16(const void* g, void* l) {
  __builtin_amdgcn_global_load_lds(
      (const __attribute__((address_space(1))) unsigned int*)g,
      (__attribute__((address_space(3))) unsigned int*)l,
      16, 0, 0);
}

DEV short8 ld_g8(const unsigned short* p) { return *(const short8*)p; }
DEV short8 ld_s8(const unsigned short* p) { return *(const short8*)p; }
DEV half4 ld_h4(const unsigned short* p) {
  half4 r; __builtin_memcpy(&r, p, 8); return r;
}

// ---------- mask dtype detection ----------
// fmt: 0 = packed bool bytes, 1 = int32 0/1, 2 = float32 0.0/1.0
__global__ void detect_mask_fmt(const unsigned int* __restrict__ mask, int* __restrict__ flag) {
  if (threadIdx.x == 0 && blockIdx.x == 0) {
    int fmt = 1;
    for (int i = 0; i < 256; ++i) {
      unsigned u = mask[i];
      if (u == 0x3F800000u) { fmt = 2; break; }
      if ((u & 0xFFFFFF00u) != 0u) { fmt = 0; break; }
    }
    *flag = fmt;
  }
}

// ---------- mask -> packed bits pm[(bh*64 + t)*2048 + q], bit j = mask[q][32t+j] ----------
__global__ void pack_mask(const unsigned char* __restrict__ m8,
                          const unsigned int* __restrict__ m32,
                          const int* __restrict__ mfmt,
                          unsigned int* __restrict__ pm) {
  __shared__ unsigned int tile[32 * 65];
  const int bh = blockIdx.x >> 6;
  const int q0 = (blockIdx.x & 63) * 32;
  const int fmt = *mfmt;
  const int tid = threadIdx.x;
#pragma unroll
  for (int rnd = 0; rnd < 8; ++rnd) {
    int w = tid + rnd * 256;               // 0..2047
    int q = w >> 6, t = w & 63;
    size_t sb = ((size_t)(bh * 2048 + q0 + q)) * 2048 + t * 32;
    unsigned bits = 0;
    if (fmt == 0) {
      uint4 a = *(const uint4*)(m8 + sb);
      uint4 bq = *(const uint4*)(m8 + sb + 16);
      unsigned wa0 = a.x, wa1 = a.y, wa2 = a.z, wa3 = a.w;
      unsigned wb0 = bq.x, wb1 = bq.y, wb2 = bq.z, wb3 = bq.w;
#pragma unroll
      for (int e = 0; e < 4; ++e) {
        bits |= (((wa0 >> (8 * e)) & 0xFFu) ? 1u : 0u) << (0 + e);
        bits |= (((wa1 >> (8 * e)) & 0xFFu) ? 1u : 0u) << (4 + e);
        bits |= (((wa2 >> (8 * e)) & 0xFFu) ? 1u : 0u) << (8 + e);
        bits |= (((wa3 >> (8 * e)) & 0xFFu) ? 1u : 0u) << (12 + e);
        bits |= (((wb0 >> (8 * e)) & 0xFFu) ? 1u : 0u) << (16 + e);
        bits |= (((wb1 >> (8 * e)) & 0xFFu) ? 1u : 0u) << (20 + e);
        bits |= (((wb2 >> (8 * e)) & 0xFFu) ? 1u : 0u) << (24 + e);
        bits |= (((wb3 >> (8 * e)) & 0xFFu) ? 1u : 0u) << (28 + e);
      }
    } else {
#pragma unroll
      for (int c = 0; c < 8; ++c) {
        uint4 v = *(const uint4*)(m32 + sb + c * 4);
        bits |= (v.x ? 1u : 0u) << (c * 4);
        bits |= (v.y ? 1u : 0u) << (c * 4 + 1);
        bits |= (v.z ? 1u : 0u) << (c * 4 + 2);
        bits |= (v.w ? 1u : 0u) << (c * 4 + 3);
      }
    }
    tile[q * 65 + t] = bits;
  }
  __syncthreads();
#pragma unroll
  for (int rnd = 0; rnd < 8; ++rnd) {
    int w = tid + rnd * 256;
    int t = w >> 5, q = w & 31;
    pm[((size_t)bh * 64 + t) * 2048 + q0 + q] = tile[q * 65 + t];
  }
}

// ---------- fused fp32 -> bf16 convert (all 7 tensors, one launch) ----------
__global__ void cvt_all(const float* __restrict__ q, const float* __restrict__ k,
                        const float* __restrict__ v,
                        const float* __restrict__ wq, const float* __restrict__ wk,
                        const float* __restrict__ wv, const float* __restrict__ wo,
                        unsigned short* __restrict__ Xq, unsigned short* __restrict__ Xk,
                        unsigned short* __restrict__ Xv, unsigned short* __restrict__ Wqb,
                        unsigned short* __restrict__ Wkb, unsigned short* __restrict__ Wvb,
                        unsigned short* __restrict__ Wob) {
  int i = blockIdx.x * 256 + threadIdx.x;
  const float* src; unsigned short* dst; int off;
  if (i < 1048576)      { src = q;  dst = Xq;  off = i; }
  else if (i < 2097152) { src = k;  dst = Xk;  off = i - 1048576; }
  else if (i < 3145728) { src = v;  dst = Xv;  off = i - 2097152; }
  else if (i < 3407872) { src = wq; dst = Wqb; off = i - 3145728; }
  else if (i < 3670016) { src = wk; dst = Wkb; off = i - 3407872; }
  else if (i < 3932160) { src = wv; dst = Wvb; off = i - 3670016; }
  else                  { src = wo; dst = Wob; off = i - 3932160; }
  float4 vv = ((const float4*)src)[off];
  ushort4_t r;
  r.x = f2bf(vv.x); r.y = f2bf(vv.y); r.z = f2bf(vv.z); r.w = f2bf(vv.w);
  ((ushort4_t*)dst)[off] = r;
}

// ---------- fused QKV projection GEMM ----------
// sel 0/1 (Q,K): bf16 out[b,h,n,d].  sel 2 (V): swapped operands -> V^T stored as
// FP16 VP_T[bh][d][n] with coalesced writes.
__global__ __launch_bounds__(256, 2) void proj_gemm(
    const unsigned short* __restrict__ Xq, const unsigned short* __restrict__ Xk,
    const unsigned short* __restrict__ Xv,
    const unsigned short* __restrict__ Wqb, const unsigned short* __restrict__ Wkb,
    const unsigned short* __restrict__ Wvb,
    const float* __restrict__ bq, const float* __restrict__ bk, const float* __restrict__ bv,
    unsigned short* __restrict__ QP, unsigned short* __restrict__ KP,
    unsigned short* __restrict__ VT) {
  const int tid = threadIdx.x;
  const int wid = tid >> 6, lane = tid & 63;
  const int l16 = lane & 15, hi = lane >> 4;
  const int m0 = blockIdx.x * 128;
  const int sel = blockIdx.y >> 3;
  const int n0 = (blockIdx.y & 7) * 128;

  const unsigned short* X; const unsigned short* W; const float* bias; unsigned short* out;
  if (sel == 0)      { X = Xq; W = Wqb; bias = bq; out = QP; }
  else if (sel == 1) { X = Xk; W = Wkb; bias = bk; out = KP; }
  else               { X = Xv; W = Wvb; bias = bv; out = VT; }

  __shared__ unsigned short stage[2 * 128 * 32];  // X tile @0, W tile @4096

  f32x4 acc[4][4] = {};
  const int wm = (wid >> 1) * 64, wn = (wid & 1) * 64;
  const int aoff = (sel == 2) ? 4096 : 0;   // V: A-frag from W tile
  const int boff = 4096 - aoff;

  for (int kt = 0; kt < 1024; kt += 32) {
#pragma unroll
    for (int t = 0; t < 4; ++t) {
      int g = wid * 4 + t;
      int c = g & 7;
      int row = c * 16 + (lane >> 2);
      int ko = (lane & 3) * 8;
      const unsigned short* src = (g < 8)
          ? (X + (size_t)(m0 + row) * 1024 + kt + ko)
          : (W + (size_t)(n0 + row) * 1024 + kt + ko);
      gload_lds16(src, (unsigned short*)((char*)stage + g * 1024));
    }
    __syncthreads();

    short8 af[4], bfr[4];
#pragma unroll
    for (int i = 0; i < 4; ++i)
      af[i] = ld_s8(&stage[aoff + (wm + i * 16 + l16) * 32 + hi * 8]);
#pragma unroll
    for (int j = 0; j < 4; ++j)
      bfr[j] = ld_s8(&stage[boff + (wn + j * 16 + l16) * 32 + hi * 8]);
#pragma unroll
    for (int i = 0; i < 4; ++i)
#pragma unroll
      for (int j = 0; j < 4; ++j)
        acc[i][j] = __builtin_amdgcn_mfma_f32_16x16x32_bf16(af[i], bfr[j], acc[i][j], 0, 0, 0);
    __syncthreads();
  }

  if (sel != 2) {
#pragma unroll
    for (int j = 0; j < 4; ++j) {
      int feat = n0 + wn + j * 16 + l16;
      float bi = bias[feat];
      int h = feat >> 6, d = feat & 63;
#pragma unroll
      for (int i = 0; i < 4; ++i) {
#pragma unroll
        for (int r = 0; r < 4; ++r) {
          int m = m0 + wm + i * 16 + hi * 4 + r;
          int b = m >> 11, n = m & 2047;
          float v = acc[i][j][r] + bi;
          out[(((size_t)(b * 16 + h)) * 2048 + n) * 64 + d] = f2bf(v);
        }
      }
    }
  } else {
#pragma unroll
    for (int j = 0; j < 4; ++j) {
      int tc0 = m0 + wn + j * 16;
      int b = tc0 >> 11, n = tc0 & 2047;
#pragma unroll
      for (int i = 0; i < 4; ++i) {
#pragma unroll
        for (int r = 0; r < 4; ++r) {
          int feat = n0 + wm + i * 16 + hi * 4 + r;
          int h = feat >> 6, d = feat & 63;
          float v = acc[i][j][r] + bias[feat];
          out[((size_t)(b * 16 + h) * 64 + d) * 2048 + n + l16] = f2h(v);
        }
      }
    }
  }
}

// ---------- flash attention: 32x32 MFMA, lane-local softmax & P (measured best) ----------
// grid 512: bid = qt*32 + bh. block 256 = 4 waves x 32 q = 128 q. KBLK=32, 64 iters.
// S^T = mfma32(K,Q): lane q = lane&31, k = (reg&3)+8*(reg>>2)+4*(lane>>5).
// PV with permuted-k fragments: P = contiguous regs (zero shuffles, zero P-LDS).
__global__ __launch_bounds__(256, 2) void attn_kernel(
    const unsigned short* __restrict__ Q, const unsigned short* __restrict__ K,
    const unsigned short* __restrict__ VT,
    const float* __restrict__ weights,
    const unsigned int* __restrict__ pm,
    unsigned short* __restrict__ O) {
  const int bid = blockIdx.x;
  const int qt = bid >> 5, bh = bid & 31;
  const int b = bh >> 4, h = bh & 15;
  const int tid = threadIdx.x, wid = tid >> 6, lane = tid & 63;
  const int l31 = lane & 31, hh = lane >> 5;
  const size_t bh_nd = (size_t)bh * 2048 * 64;
  const int q0 = qt * 128;
  const int qg = q0 + wid * 32 + l31;      // this lane's q row

  // Q fragments: B-operand, col=q=l31, d = 16j + 8*hh + e
  short8 qf0 = ld_g8(Q + bh_nd + (size_t)qg * 64 + 0  + hh * 8);
  short8 qf1 = ld_g8(Q + bh_nd + (size_t)qg * 64 + 16 + hh * 8);
  short8 qf2 = ld_g8(Q + bh_nd + (size_t)qg * 64 + 32 + hh * 8);
  short8 qf3 = ld_g8(Q + bh_nd + (size_t)qg * 64 + 48 + hh * 8);

  __shared__ float wlds[2][128 * 32];           // 16 KB each, XOR-swizzled
  __shared__ unsigned short vlds[2][64 * 32];   // 4 KB each (f16), XOR-swizzled

  // staging geometry (linear LDS dest = base + lane*16; swizzle baked into SOURCE)
  const float* wsrc = weights + (size_t)bh * 2048 * 2048;
  const unsigned short* vsrc = VT + bh_nd;
  const int wswz = 4 * ((lane & 7) ^ (lane >> 3));                 // floats
  const int vswz = 8 * ((lane & 3) ^ ((lane >> 3) & 3));           // u16
  const int wrow_s = q0 + wid * 32 + (lane >> 3);                  // + i*8
  const int vrow_s = wid * 16 + (lane >> 2);

#define STAGE(NXT, KT)                                                        \
  {                                                                           \
    _Pragma("unroll")                                                         \
    for (int i = 0; i < 4; ++i)                                               \
      gload_lds16(wsrc + (size_t)(wrow_s + i * 8) * 2048 + (KT) + wswz,       \
                  &wlds[NXT][(wid * 4 + i) * 256]);                           \
    gload_lds16(vsrc + (size_t)vrow_s * 2048 + (KT) + vswz,                   \
                &vlds[NXT][wid * 512]);                                       \
  }

  f32x16 o0 = {}, o1 = {};
  float mrow = -1e30f, lrow = 0.f;

  STAGE(0, 0)
  __syncthreads();

  for (int t = 0; t < 64; ++t) {
    const int cur = t & 1;
    const int kt0 = t * 32;

    // ---- K fragments (A-operand: row k = l31, d = 16j + 8hh + e)
    short8 kf0 = ld_g8(K + bh_nd + (size_t)(kt0 + l31) * 64 + 0  + hh * 8);
    short8 kf1 = ld_g8(K + bh_nd + (size_t)(kt0 + l31) * 64 + 16 + hh * 8);
    short8 kf2 = ld_g8(K + bh_nd + (size_t)(kt0 + l31) * 64 + 32 + hh * 8);
    short8 kf3 = ld_g8(K + bh_nd + (size_t)(kt0 + l31) * 64 + 48 + hh * 8);
    unsigned mw = pm[((size_t)bh * 64 + t) * 2048 + qg];

    // ---- issue next tile's staging (stays in flight under compute)
    if (t < 63) STAGE(cur ^ 1, kt0 + 32)

    // ---- QK^T (S^T): 4 chained mfma over d
    f32x16 s = {};
    s = __builtin_amdgcn_mfma_f32_32x32x16_bf16(kf0, qf0, s, 0, 0, 0);
    s = __builtin_amdgcn_mfma_f32_32x32x16_bf16(kf1, qf1, s, 0, 0, 0);
    s = __builtin_amdgcn_mfma_f32_32x32x16_bf16(kf2, qf2, s, 0, 0, 0);
    s = __builtin_amdgcn_mfma_f32_32x32x16_bf16(kf3, qf3, s, 0, 0, 0);

    // ---- weights from swizzled LDS (4x b128, conflict-free phases)
    const float* wrow = &wlds[cur][(wid * 32 + l31) * 32];
    f32x4 wv[4];
    wv[0] = *(const f32x4*)&wrow[4 * ((hh + 0) ^ (l31 & 7))];
    wv[1] = *(const f32x4*)&wrow[4 * ((hh + 2) ^ (l31 & 7))];
    wv[2] = *(const f32x4*)&wrow[4 * ((hh + 4) ^ (l31 & 7))];
    wv[3] = *(const f32x4*)&wrow[4 * ((hh + 6) ^ (l31 & 7))];

    // ---- apply scale*weights + mask (branchless; reg r <-> k=(r&3)+8*(r>>2)+4hh)
    unsigned mb = mw >> (4 * hh);
#pragma unroll
    for (int r = 0; r < 16; ++r) {
      bool mk = (mb >> ((r & 3) + 8 * (r >> 2))) & 1;
      s[r] = mk ? -INFINITY : s[r] * 0.125f * wv[r >> 2][r & 3];
    }

    // ---- online softmax: lane-local 16, 1 shfl for the pair, skip-rescale
    float tm = s[0];
#pragma unroll
    for (int r = 1; r < 16; ++r) tm = fmaxf(tm, s[r]);
    float tm2 = fmaxf(tm, __shfl_xor(tm, 32));
    if (__any(tm2 > mrow)) {
      float mnew = fmaxf(mrow, tm2);
      float sc = __expf(mrow - mnew);
      lrow *= sc;
      o0 *= sc;
      o1 *= sc;
      mrow = mnew;
    }
    float ps = 0.f;
#pragma unroll
    for (int r = 0; r < 16; ++r) {
      s[r] = __expf(s[r] - mrow);
      ps += s[r];
    }
    lrow += ps;   // per-half; merged in epilogue

    // ---- P -> f16 fragments (contiguous regs; zero cross-lane)
    half8 pa0, pa1;
#pragma unroll
    for (int r = 0; r < 8; ++r) {
      pa0[r] = (_Float16)s[r];
      pa1[r] = (_Float16)s[8 + r];
    }

    // ---- PV: O^T += V'~ P~ (permuted k; V from swizzled LDS)
    {
      const unsigned short* vr = &vlds[cur][l31 * 32];
      half4 a0 = ld_h4(&vr[4 * ((hh + 0) ^ (l31 & 6))]);
      half4 a1 = ld_h4(&vr[4 * ((hh + 2) ^ (l31 & 6))]);
      half8 vf;
#pragma unroll
      for (int e = 0; e < 4; ++e) { vf[e] = a0[e]; vf[4 + e] = a1[e]; }
      o0 = __builtin_amdgcn_mfma_f32_32x32x16_f16(vf, pa0, o0, 0, 0, 0);
      half4 b0 = ld_h4(&vr[4 * ((hh + 4) ^ (l31 & 6))]);
      half4 b1 = ld_h4(&vr[4 * ((hh + 6) ^ (l31 & 6))]);
#pragma unroll
      for (int e = 0; e < 4; ++e) { vf[e] = b0[e]; vf[4 + e] = b1[e]; }
      o0 = __builtin_amdgcn_mfma_f32_32x32x16_f16(vf, pa1, o0, 0, 0, 0);
    }
    {
      const unsigned short* vr = &vlds[cur][(32 + l31) * 32];
      half4 a0 = ld_h4(&vr[4 * ((hh + 0) ^ (l31 & 6))]);
      half4 a1 = ld_h4(&vr[4 * ((hh + 2) ^ (l31 & 6))]);
      half8 vf;
#pragma unroll
      for (int e = 0; e < 4; ++e) { vf[e] = a0[e]; vf[4 + e] = a1[e]; }
      o1 = __builtin_amdgcn_mfma_f32_32x32x16_f16(vf, pa0, o1, 0, 0, 0);
      half4 b0 = ld_h4(&vr[4 * ((hh + 4) ^ (l31 & 6))]);
      half4 b1 = ld_h4(&vr[4 * ((hh + 6) ^ (l31 & 6))]);
#pragma unroll
      for (int e = 0; e < 4; ++e) { vf[e] = b0[e]; vf[4 + e] = b1[e]; }
      o1 = __builtin_amdgcn_mfma_f32_32x32x16_f16(vf, pa1, o1, 0, 0, 0);
    }

    __syncthreads();
  }

  // ---- epilogue: merge pair-sums, normalize, store bf16
  lrow += __shfl_xor(lrow, 32);
  float inv = 1.0f / lrow;
  const size_t ob = (size_t)(b * 2048 + qg) * 1024 + h * 64;
#pragma unroll
  for (int j = 0; j < 4; ++j) {
    ushort4_t pk;
    pk.x = f2bf(o0[4 * j + 0] * inv); pk.y = f2bf(o0[4 * j + 1] * inv);
    pk.z = f2bf(o0[4 * j + 2] * inv); pk.w = f2bf(o0[4 * j + 3] * inv);
    *(ushort4_t*)&O[ob + 8 * j + 4 * hh] = pk;
    ushort4_t pk1;
    pk1.x = f2bf(o1[4 * j + 0] * inv); pk1.y = f2bf(o1[4 * j + 1] * inv);
    pk1.z = f2bf(o1[4 * j + 2] * inv); pk1.w = f2bf(o1[4 * j + 3] * inv);
    *(ushort4_t*)&O[ob + 32 + 8 * j + 4 * hh] = pk1;
  }
#undef STAGE
}

// ---------- output projection GEMM (fp32 out) ----------
__global__ __launch_bounds__(256, 2) void out_gemm(
    const unsigned short* __restrict__ A, const unsigned short* __restrict__ W,
    const float* __restrict__ bias, float* __restrict__ Cout) {
  const int tid = threadIdx.x;
  const int wid = tid >> 6, lane = tid & 63;
  const int l16 = lane & 15, hi = lane >> 4;
  const int m0 = blockIdx.x * 128;
  const int n0 = blockIdx.y * 128;

  __shared__ unsigned short stage[2 * 128 * 32];
  f32x4 acc[4][4] = {};
  const int wm = (wid >> 1) * 64, wn = (wid & 1) * 64;

  for (int kt = 0; kt < 1024; kt += 32) {
#pragma unroll
    for (int t = 0; t < 4; ++t) {
      int g = wid * 4 + t;
      int c = g & 7;
      int row = c * 16 + (lane >> 2);
      int ko = (lane & 3) * 8;
      const unsigned short* src = (g < 8)
          ? (A + (size_t)(m0 + row) * 1024 + kt + ko)
          : (W + (size_t)(n0 + row) * 1024 + kt + ko);
      gload_lds16(src, (unsigned short*)((char*)stage + g * 1024));
    }
    __syncthreads();

    short8 af[4], bfr[4];
#pragma unroll
    for (int i = 0; i < 4; ++i)
      af[i] = ld_s8(&stage[(wm + i * 16 + l16) * 32 + hi * 8]);
#pragma unroll
    for (int j = 0; j < 4; ++j)
      bfr[j] = ld_s8(&stage[4096 + (wn + j * 16 + l16) * 32 + hi * 8]);
#pragma unroll
    for (int i = 0; i < 4; ++i)
#pragma unroll
      for (int j = 0; j < 4; ++j)
        acc[i][j] = __builtin_amdgcn_mfma_f32_16x16x32_bf16(af[i], bfr[j], acc[i][j], 0, 0, 0);
    __syncthreads();
  }

#pragma unroll
  for (int j = 0; j < 4; ++j) {
    int feat = n0 + wn + j * 16 + l16;
    float bi = bias[feat];
#pragma unroll
    for (int i = 0; i < 4; ++i) {
#pragma unroll
      for (int r = 0; r < 4; ++r) {
        int m = m0 + wm + i * 16 + hi * 4 + r;
        Cout[(size_t)m * 1024 + feat] = acc[i][j][r] + bi;
      }
    }
  }
}

// ---------- launch ----------
extern "C" void kernel_launch(void* const* d_in, const int* in_sizes, int n_in,
                              void* d_out, int out_size, void* d_ws, size_t ws_size,
                              hipStream_t stream) {
  const float* queries = (const float*)d_in[0];
  const float* keys    = (const float*)d_in[1];
  const float* values  = (const float*)d_in[2];
  const void*  maskp   = d_in[3];
  const float* weights = (const float*)d_in[4];
  const float* Wq = (const float*)d_in[5];
  const float* bq = (const float*)d_in[6];
  const float* Wk = (const float*)d_in[7];
  const float* bk = (const float*)d_in[8];
  const float* Wv = (const float*)d_in[9];
  const float* bv = (const float*)d_in[10];
  const float* Wo = (const float*)d_in[11];
  const float* bo = (const float*)d_in[12];

  unsigned short* ws = (unsigned short*)d_ws;
  unsigned short* Xq  = ws;                 // 4194304 u16 each
  unsigned short* Xk  = ws + 4194304;
  unsigned short* Xv  = ws + 8388608;
  unsigned short* Wqb = ws + 12582912;      // 1048576 u16 each
  unsigned short* Wkb = ws + 13631488;
  unsigned short* Wvb = ws + 14680064;
  unsigned short* Wob = ws + 15728640;
  unsigned short* QP  = ws + 16777216;      // (b,h,n,d) bf16
  unsigned short* KP  = ws + 20971520;      // (b,h,n,d) bf16
  unsigned short* VPT = ws + 25165824;      // (b,h,d,n) fp16
  unsigned short* OB  = Xq;                 // reuse (dead after proj_gemm)
  unsigned int* pmb   = (unsigned int*)(ws + 4194304);  // aliases Xk+Xv (dead after proj)
  int* mflag = (int*)(ws + 29360128);

  detect_mask_fmt<<<1, 64, 0, stream>>>((const unsigned int*)maskp, mflag);

  cvt_all<<<16384, 256, 0, stream>>>(queries, keys, values, Wq, Wk, Wv, Wo,
                                     Xq, Xk, Xv, Wqb, Wkb, Wvb, Wob);

  proj_gemm<<<dim3(32, 24), 256, 0, stream>>>(Xq, Xk, Xv, Wqb, Wkb, Wvb,
                                              bq, bk, bv, QP, KP, VPT);

  pack_mask<<<2048, 256, 0, stream>>>((const unsigned char*)maskp,
                                      (const unsigned int*)maskp, mflag, pmb);

  attn_kernel<<<512, 256, 0, stream>>>(QP, KP, VPT, weights, pmb, OB);

  out_gemm<<<dim3(32, 8), 256, 0, stream>>>(OB, Wob, bo, (float*)d_out);
}